// Round 13
// baseline (74.759 us; speedup 1.0000x reference)
//
#include <hip/hip_runtime.h>
#include <hip/hip_bf16.h>

#define N 8192
#define D 128
#define NJS 8    // j-tiles of 128 per block (block covers 1024 cols)
#define LN2 0.69314718056f

typedef __bf16 bf16x8 __attribute__((ext_vector_type(8)));
typedef float f32x4 __attribute__((ext_vector_type(4)));
typedef unsigned int u32;

// async global->LDS, 16B/lane; LDS dest = wave-uniform base + lane*16,
// global src per-lane (m173: swizzle lives on the SOURCE address).
__device__ __forceinline__ void gload_lds16(const void* g, void* l) {
    __builtin_amdgcn_global_load_lds(
        (const __attribute__((address_space(1))) u32*)g,
        (__attribute__((address_space(3))) u32*)l, 16, 0, 0);
}

// Kernel 1: row-normalize (fp32 -> bf16), pre-scaled by rsqrt(T*ln2) so
// downstream dot products equal logits*log2(e). Global label histogram
// (fp32 atomics, exact integer counts — R1-proven). Zeroes tail counter.
__global__ void k_norm(const float* __restrict__ feat, const int* __restrict__ lab,
                       const float* __restrict__ tempp,
                       __hip_bfloat16* __restrict__ fbf, float* __restrict__ hist,
                       unsigned* __restrict__ counter) {
    if (blockIdx.x == 0 && threadIdx.x == 0) *counter = 0u;
    const int row  = blockIdx.x * 4 + (threadIdx.x >> 6);
    const int lane = threadIdx.x & 63;
    float2 v = *reinterpret_cast<const float2*>(&feat[row * D + lane * 2]);
    float ss = v.x * v.x + v.y * v.y;
#pragma unroll
    for (int m = 32; m; m >>= 1) ss += __shfl_xor(ss, m);
    const float sc = rsqrtf(tempp[0] * LN2);
    const float r = sc / fmaxf(sqrtf(ss), 1e-8f);
    __hip_bfloat162 o;
    o.x = __float2bfloat16(v.x * r);
    o.y = __float2bfloat16(v.y * r);
    *reinterpret_cast<__hip_bfloat162*>(&fbf[row * D + lane * 2]) = o;
    if (lane == 0) atomicAdd(&hist[lab[row]], 1.0f);
}

// Kernel 2 (IDENTICAL to R11's proven k_gemm): 512-thread blocks, 8 waves of
// 32 rows x 64 cols; A-frags register-resident; B via global_load_lds into
// 2x32KB LDS dbuf (XOR-swizzled source + swizzled ds_read); 1 barrier/tile.
__launch_bounds__(512, 4)
__global__ void k_gemm(const __hip_bfloat16* __restrict__ fbf,
                       const int* __restrict__ lab,
                       float* __restrict__ ProwS, float* __restrict__ ProwE) {
    __shared__ char Bs[65536];                    // 2 x 32KB B-tile buffers
    const int ib = blockIdx.x, js = blockIdx.y;   // same-ib blocks share XCD
    const int i0 = ib * 128;
    const int tid = threadIdx.x;
    const int wave = tid >> 6, lane = tid & 63;
    const int wm = wave >> 1, wn = wave & 1;      // wave: 32 rows x 64 cols
    const int lr = lane & 15, lg = lane >> 4;

    // A fragments resident: rows i0 + wm*32 + mi*16 + lr, k = ks*32 + lg*8
    const __hip_bfloat16* pa = fbf + (size_t)(i0 + wm * 32 + lr) * D + lg * 8;
    bf16x8 af[2][4];
#pragma unroll
    for (int mi = 0; mi < 2; ++mi)
#pragma unroll
        for (int ks = 0; ks < 4; ++ks)
            af[mi][ks] = *reinterpret_cast<const bf16x8*>(pa + mi * 16 * D + ks * 32);

    int4 labi[2];
#pragma unroll
    for (int mi = 0; mi < 2; ++mi)
        labi[mi] = *reinterpret_cast<const int4*>(&lab[i0 + wm * 32 + mi * 16 + lg * 4]);

    float rps[2][4] = {}, res_[2][4] = {};        // running per-row partials

    const char* fbytes = reinterpret_cast<const char*>(fbf);
    // Stage tile t into buffer (t&1): 512 lanes x 4 iters x 16B = 32KB.
    // LDS linear chunk c holds global chunk (row, (c&15)^(row&7)).
#define STAGE(t)                                                               \
    {                                                                          \
        const int j0s = js * (NJS * 128) + (t) * 128;                          \
        char* dst = Bs + ((t) & 1) * 32768;                                    \
        _Pragma("unroll")                                                      \
        for (int it = 0; it < 4; ++it) {                                       \
            const int base = (it * 8 + wave) * 64;                             \
            const int c_ = base + lane;                                        \
            const int row = c_ >> 4;                                           \
            const int kc = (c_ & 15) ^ (row & 7);                              \
            gload_lds16(fbytes + (size_t)(j0s + row) * 256 + kc * 16,          \
                        dst + base * 16);                                      \
        }                                                                      \
    }

    STAGE(0);
    __syncthreads();

    for (int t = 0; t < NJS; ++t) {
        if (t < NJS - 1) STAGE(t + 1);
        const char* buf = Bs + (t & 1) * 32768;
        const int j0 = js * (NJS * 128) + t * 128;
#pragma unroll
        for (int h = 0; h < 2; ++h) {             // two 32-col halves
            bf16x8 bfr[2][4];
            int labj[2];
#pragma unroll
            for (int nih = 0; nih < 2; ++nih) {
#pragma unroll
                for (int ks = 0; ks < 4; ++ks) {
                    const int R = wn * 64 + h * 32 + nih * 16 + lr;
                    const int kc = ks * 4 + lg;
                    bfr[nih][ks] = *reinterpret_cast<const bf16x8*>(
                        buf + R * 256 + ((kc ^ (R & 7)) << 4));
                }
                labj[nih] = lab[j0 + wn * 64 + h * 32 + nih * 16 + lr];
            }
            f32x4 acc[2][2] = {};
#pragma unroll
            for (int ks = 0; ks < 4; ++ks)
#pragma unroll
                for (int mi = 0; mi < 2; ++mi)
#pragma unroll
                    for (int nih = 0; nih < 2; ++nih)
                        acc[mi][nih] = __builtin_amdgcn_mfma_f32_16x16x32_bf16(
                            af[mi][ks], bfr[nih][ks], acc[mi][nih], 0, 0, 0);
            // C/D layout (m89): col = lane&15, row = (lane>>4)*4 + reg
#pragma unroll
            for (int mi = 0; mi < 2; ++mi)
#pragma unroll
                for (int r = 0; r < 4; ++r) {
                    const int li = reinterpret_cast<const int*>(&labi[mi])[r];
#pragma unroll
                    for (int nih = 0; nih < 2; ++nih) {
                        const float v = acc[mi][nih][r];   // logits * log2(e)
                        const float e = __builtin_amdgcn_exp2f(v);
                        const bool same = (li == labj[nih]);
                        rps[mi][r]  += same ? v : 0.0f;
                        res_[mi][r] += same ? 0.0f : e;
                    }
                }
        }
        __syncthreads();   // waves done reading buf(t&1); stage(t+1) landed
    }
#undef STAGE

    // row partials: reduce over the 16 col-lanes, write per-(js,wn) slab.
#pragma unroll
    for (int mi = 0; mi < 2; ++mi)
#pragma unroll
        for (int r = 0; r < 4; ++r) {
            float ps = rps[mi][r], es = res_[mi][r];
#pragma unroll
            for (int m = 1; m < 16; m <<= 1) {
                ps += __shfl_xor(ps, m);
                es += __shfl_xor(es, m);
            }
            if (lr == 0) {
                const int rowl = wm * 32 + mi * 16 + lg * 4 + r;
                ProwS[(size_t)(js * 2 + wn) * N + i0 + rowl] = ps;
                ProwE[(size_t)(js * 2 + wn) * N + i0 + rowl] = es;
            }
        }
}

// Kernel 3 (parallel tail, 32 blocks x 256): per-row combine over 16 slabs,
// cnt from the global hist (no per-block rebuild), block sums, last-block
// finalize via device-scope counter (deterministic).
__global__ void k_tail(const float* __restrict__ ProwS, const float* __restrict__ ProwE,
                       const int* __restrict__ lab, const float* __restrict__ hist,
                       float* __restrict__ bsums, unsigned* __restrict__ counter,
                       float* __restrict__ out) {
    const int tid = threadIdx.x;
    const int i = blockIdx.x * 256 + tid;
    float sp = 0.0f, ed = 0.0f;
#pragma unroll
    for (int s = 0; s < 16; ++s) {
        sp += ProwS[(size_t)s * N + i];
        ed += ProwE[(size_t)s * N + i];
    }
    float term = LN2 * (sp / hist[lab[i]] - __builtin_amdgcn_logf(ed));  // log2->ln
#pragma unroll
    for (int m = 32; m; m >>= 1) term += __shfl_xor(term, m);
    __shared__ float wsum[4];
    if ((tid & 63) == 0) wsum[tid >> 6] = term;
    __syncthreads();
    if (tid == 0) {
        bsums[blockIdx.x] = wsum[0] + wsum[1] + wsum[2] + wsum[3];
        __threadfence();
        const unsigned v = atomicAdd(counter, 1u);
        if (v == 31u) {
            __threadfence();
            float tt = 0.0f;
            for (int k = 0; k < 32; ++k) tt += bsums[k];
            out[0] = -(tt / (float)N);
        }
    }
}

extern "C" void kernel_launch(void* const* d_in, const int* in_sizes, int n_in,
                              void* d_out, int out_size, void* d_ws, size_t ws_size,
                              hipStream_t stream) {
    const float* feat = (const float*)d_in[0];
    const int* lab    = (const int*)d_in[1];
    const float* temp = (const float*)d_in[2];
    float* out = (float*)d_out;
    char* ws = (char*)d_ws;

    __hip_bfloat16* fbf = (__hip_bfloat16*)ws;   // 2 MB scaled bf16 features
    float* ProwS = (float*)(ws + 2097152);       // 512 KB [16][8192]
    float* ProwE = (float*)(ws + 2621440);       // 512 KB [16][8192]
    float* hist  = (float*)(ws + 3145728);       // 512 B
    float* bsums = (float*)(ws + 3146240);       // 128 B
    unsigned* counter = (unsigned*)(ws + 3146368);

    hipMemsetAsync(hist, 0, 512, stream);
    k_norm<<<N / 4, 256, 0, stream>>>(feat, lab, temp, fbf, hist, counter);
    dim3 grid(N / 128, NJS);                     // x=ib fast -> A panel XCD-hot
    k_gemm<<<grid, 512, 0, stream>>>(fbf, lab, ProwS, ProwE);
    k_tail<<<32, 256, 0, stream>>>(ProwS, ProwE, lab, hist, bsums, counter, out);
}

// Round 14
// 50.645 us; speedup vs baseline: 1.4761x; 1.4761x over previous
//
#include <hip/hip_runtime.h>
#include <hip/hip_bf16.h>

#define N 8192
#define D 128
#define NJT 16   // j-tiles of 64 cols per block (block covers 1024 cols)
#define LN2 0.69314718056f

typedef __bf16 bf16x8 __attribute__((ext_vector_type(8)));
typedef float f32x4 __attribute__((ext_vector_type(4)));
typedef unsigned int u32;

// async global->LDS, 16B/lane; LDS dest = wave-uniform base + lane*16,
// global src per-lane (m173: swizzle lives on the SOURCE address).
__device__ __forceinline__ void gload_lds16(const void* g, void* l) {
    __builtin_amdgcn_global_load_lds(
        (const __attribute__((address_space(1))) u32*)g,
        (__attribute__((address_space(3))) u32*)l, 16, 0, 0);
}

// Kernel 1: row-normalize (fp32 -> bf16), pre-scaled by rsqrt(T*ln2) so
// downstream dot products equal logits*log2(e). Zeroes tail counter.
__global__ void k_norm(const float* __restrict__ feat, const float* __restrict__ tempp,
                       __hip_bfloat16* __restrict__ fbf, unsigned* __restrict__ counter) {
    if (blockIdx.x == 0 && threadIdx.x == 0) *counter = 0u;
    const int row  = blockIdx.x * 4 + (threadIdx.x >> 6);
    const int lane = threadIdx.x & 63;
    float2 v = *reinterpret_cast<const float2*>(&feat[row * D + lane * 2]);
    float ss = v.x * v.x + v.y * v.y;
#pragma unroll
    for (int m = 32; m; m >>= 1) ss += __shfl_xor(ss, m);
    const float sc = rsqrtf(tempp[0] * LN2);
    const float r = sc / fmaxf(sqrtf(ss), 1e-8f);
    __hip_bfloat162 o;
    o.x = __float2bfloat16(v.x * r);
    o.y = __float2bfloat16(v.y * r);
    *reinterpret_cast<__hip_bfloat162*>(&fbf[row * D + lane * 2]) = o;
}

// Kernel 2: R11 skeleton with HALF-WIDTH tiles for doubled occupancy.
// 512 threads = 8 waves; wave owns 32 rows x 32 cols of each 128x64 tile.
// LDS = 2 x 16KB dbuf -> 32KB/block -> 4 blocks/CU = 8 waves/SIMD (VGPR 64).
// B staged via global_load_lds (XOR-swizzled source + swizzled ds_read);
// 1 barrier/tile, 16 tiles.
__launch_bounds__(512, 4)
__global__ void k_gemm(const __hip_bfloat16* __restrict__ fbf,
                       const int* __restrict__ lab,
                       float* __restrict__ ProwS, float* __restrict__ ProwE) {
    __shared__ char Bs[32768];                    // 2 x 16KB B-tile buffers
    const int ib = blockIdx.x, js = blockIdx.y;   // same-ib blocks share XCD
    const int i0 = ib * 128;
    const int tid = threadIdx.x;
    const int wave = tid >> 6, lane = tid & 63;
    const int wm = wave >> 1, wn = wave & 1;      // wave: 32 rows x 32 cols
    const int lr = lane & 15, lg = lane >> 4;

    // A fragments resident: rows i0 + wm*32 + mi*16 + lr, k = ks*32 + lg*8
    const __hip_bfloat16* pa = fbf + (size_t)(i0 + wm * 32 + lr) * D + lg * 8;
    bf16x8 af[2][4];
#pragma unroll
    for (int mi = 0; mi < 2; ++mi)
#pragma unroll
        for (int ks = 0; ks < 4; ++ks)
            af[mi][ks] = *reinterpret_cast<const bf16x8*>(pa + mi * 16 * D + ks * 32);

    int4 labi[2];
#pragma unroll
    for (int mi = 0; mi < 2; ++mi)
        labi[mi] = *reinterpret_cast<const int4*>(&lab[i0 + wm * 32 + mi * 16 + lg * 4]);

    float rps[2][4] = {}, res_[2][4] = {};        // running per-row partials

    const char* fbytes = reinterpret_cast<const char*>(fbf);
    // Stage tile t (64 j-rows x 256B) into buffer (t&1): 512 lanes x 2 x 16B.
    // LDS linear chunk c holds global chunk (row, (c&15)^(row&7)).
#define STAGE(t)                                                               \
    {                                                                          \
        const int j0s = js * (NJT * 64) + (t) * 64;                            \
        char* dst = Bs + ((t) & 1) * 16384;                                    \
        _Pragma("unroll")                                                      \
        for (int it = 0; it < 2; ++it) {                                       \
            const int base = (it * 8 + wave) * 64;                             \
            const int c_ = base + lane;                                        \
            const int row = c_ >> 4;                                           \
            const int kc = (c_ & 15) ^ (row & 7);                              \
            gload_lds16(fbytes + (size_t)(j0s + row) * 256 + kc * 16,          \
                        dst + base * 16);                                      \
        }                                                                      \
    }

    STAGE(0);
    __syncthreads();

    for (int t = 0; t < NJT; ++t) {
        if (t < NJT - 1) STAGE(t + 1);
        const char* buf = Bs + (t & 1) * 16384;
        const int j0 = js * (NJT * 64) + t * 64;
        bf16x8 bfr[2][4];
        int labj[2];
#pragma unroll
        for (int nih = 0; nih < 2; ++nih) {
#pragma unroll
            for (int ks = 0; ks < 4; ++ks) {
                const int R = wn * 32 + nih * 16 + lr;    // 0..63
                const int kc = ks * 4 + lg;
                bfr[nih][ks] = *reinterpret_cast<const bf16x8*>(
                    buf + R * 256 + ((kc ^ (R & 7)) << 4));
            }
            labj[nih] = lab[j0 + wn * 32 + nih * 16 + lr];
        }
        f32x4 acc[2][2] = {};
#pragma unroll
        for (int ks = 0; ks < 4; ++ks)
#pragma unroll
            for (int mi = 0; mi < 2; ++mi)
#pragma unroll
                for (int nih = 0; nih < 2; ++nih)
                    acc[mi][nih] = __builtin_amdgcn_mfma_f32_16x16x32_bf16(
                        af[mi][ks], bfr[nih][ks], acc[mi][nih], 0, 0, 0);
        // C/D layout (m89): col = lane&15, row = (lane>>4)*4 + reg
#pragma unroll
        for (int mi = 0; mi < 2; ++mi)
#pragma unroll
            for (int r = 0; r < 4; ++r) {
                const int li = reinterpret_cast<const int*>(&labi[mi])[r];
#pragma unroll
                for (int nih = 0; nih < 2; ++nih) {
                    const float v = acc[mi][nih][r];   // logits * log2(e)
                    const float e = __builtin_amdgcn_exp2f(v);
                    const bool same = (li == labj[nih]);
                    rps[mi][r]  += same ? v : 0.0f;
                    res_[mi][r] += same ? 0.0f : e;
                }
            }
        __syncthreads();   // waves done reading buf(t&1); stage(t+1) landed
    }
#undef STAGE

    // row partials: reduce over the 16 col-lanes, write per-(js,wn) slab.
    // Waves with different wm own disjoint rows -> no cross-wave combine.
#pragma unroll
    for (int mi = 0; mi < 2; ++mi)
#pragma unroll
        for (int r = 0; r < 4; ++r) {
            float ps = rps[mi][r], es = res_[mi][r];
#pragma unroll
            for (int m = 1; m < 16; m <<= 1) {
                ps += __shfl_xor(ps, m);
                es += __shfl_xor(es, m);
            }
            if (lr == 0) {
                const int rowl = wm * 32 + mi * 16 + lg * 4 + r;
                ProwS[(size_t)(js * 2 + wn) * N + i0 + rowl] = ps;
                ProwE[(size_t)(js * 2 + wn) * N + i0 + rowl] = es;
            }
        }
}

// Kernel 3 (parallel tail, 32 blocks x 256, R11-proven): per-block LDS label
// histogram, per-row combine over 16 slabs, block sums, last-block finalize.
__global__ void k_tail(const float* __restrict__ ProwS, const float* __restrict__ ProwE,
                       const int* __restrict__ lab,
                       float* __restrict__ bsums, unsigned* __restrict__ counter,
                       float* __restrict__ out) {
    __shared__ float hist[128];
    __shared__ float wsum[4];
    const int tid = threadIdx.x;
    if (tid < 128) hist[tid] = 0.0f;
    __syncthreads();
#pragma unroll
    for (int k = 0; k < 32; ++k) atomicAdd(&hist[lab[tid + k * 256]], 1.0f);
    __syncthreads();

    const int i = blockIdx.x * 256 + tid;
    float sp = 0.0f, ed = 0.0f;
#pragma unroll
    for (int s = 0; s < 16; ++s) {
        sp += ProwS[(size_t)s * N + i];
        ed += ProwE[(size_t)s * N + i];
    }
    float term = LN2 * (sp / hist[lab[i]] - __builtin_amdgcn_logf(ed));  // log2->ln
#pragma unroll
    for (int m = 32; m; m >>= 1) term += __shfl_xor(term, m);
    if ((tid & 63) == 0) wsum[tid >> 6] = term;
    __syncthreads();
    if (tid == 0) {
        bsums[blockIdx.x] = wsum[0] + wsum[1] + wsum[2] + wsum[3];
        __threadfence();
        const unsigned v = atomicAdd(counter, 1u);
        if (v == 31u) {
            __threadfence();
            float tt = 0.0f;
            for (int k = 0; k < 32; ++k) tt += bsums[k];
            out[0] = -(tt / (float)N);
        }
    }
}

extern "C" void kernel_launch(void* const* d_in, const int* in_sizes, int n_in,
                              void* d_out, int out_size, void* d_ws, size_t ws_size,
                              hipStream_t stream) {
    const float* feat = (const float*)d_in[0];
    const int* lab    = (const int*)d_in[1];
    const float* temp = (const float*)d_in[2];
    float* out = (float*)d_out;
    char* ws = (char*)d_ws;

    __hip_bfloat16* fbf = (__hip_bfloat16*)ws;   // 2 MB scaled bf16 features
    float* ProwS = (float*)(ws + 2097152);       // 512 KB [16][8192]
    float* ProwE = (float*)(ws + 2621440);       // 512 KB [16][8192]
    float* bsums = (float*)(ws + 3145728);       // 128 B
    unsigned* counter = (unsigned*)(ws + 3145856);

    k_norm<<<N / 4, 256, 0, stream>>>(feat, temp, fbf, counter);
    dim3 grid(N / 128, NJT * 64 * 8 / 1024 / 8 + 7);  // placeholder avoided below
    dim3 g2(N / 128, 8);                          // 64 x 8: block covers 1024 cols
    k_gemm<<<g2, 512, 0, stream>>>(fbf, lab, ProwS, ProwE);
    k_tail<<<32, 256, 0, stream>>>(ProwS, ProwE, lab, bsums, counter, out);
}